// Round 1
// baseline (24000.652 us; speedup 1.0000x reference)
//
#include <hip/hip_runtime.h>
#include <math.h>

#define BSZ 4
#define FCH 1024
#define SEQ 2048
#define ICH 2048
#define KW  5
#define EPSV 1e-5f

__device__ __forceinline__ float wave_reduce_add(float x) {
#pragma unroll
  for (int off = 32; off > 0; off >>= 1)
    x += __shfl_xor(x, off, 64);
  return x;
}

// x[b,f,s] = inp[b,f,s] + pos[f,s]
__global__ __launch_bounds__(256) void add_pos_kernel(
    const float* __restrict__ inp, const float* __restrict__ pos,
    float* __restrict__ x)
{
  const size_t fs = (size_t)FCH * SEQ;
  const size_t total = (size_t)BSZ * fs;
  for (size_t i = (size_t)blockIdx.x * blockDim.x + threadIdx.x;
       i < total; i += (size_t)gridDim.x * blockDim.x)
    x[i] = inp[i] + pos[i % fs];
}

// C[b,m,s] (+)= sum_k W[m*sWm + k*sWk] * X[b,k,s+shift]   (zero-pad s+shift<0)
// 64x64 tile, 256 threads, 4x4 micro-tile per thread, BK=16.
__global__ __launch_bounds__(256) void gemm_shift_kernel(
    const float* __restrict__ W, int sWm, int sWk,
    const float* __restrict__ X, float* __restrict__ C,
    int M, int Kd, int shift, int accumulate)
{
  __shared__ __align__(16) float As[16][64];
  __shared__ __align__(16) float Bs[16][64];

  const int b  = blockIdx.z;
  const int m0 = blockIdx.y * 64;
  const int n0 = blockIdx.x * 64;
  const float* __restrict__ Xb = X + (size_t)b * Kd * SEQ;
  float* __restrict__ Cb = C + (size_t)b * M * SEQ;

  const int tid = threadIdx.x;
  const int tx = tid & 15;        // micro-col group
  const int ty = tid >> 4;        // micro-row group

  // A-load mapping: m = tid>>2 (0..63), kk = (tid&3)*4 + u
  const int am = tid >> 2;
  const int ak = (tid & 3) * 4;
  // B-load mapping: n = tid&63, kk = (tid>>6)*4 + u
  const int bn = tid & 63;
  const int bk = (tid >> 6) * 4;
  const int bc = n0 + bn + shift; // shifted source column (constant per thread)

  float acc[4][4] = {};

  for (int k0 = 0; k0 < Kd; k0 += 16) {
#pragma unroll
    for (int u = 0; u < 4; ++u)
      As[ak + u][am] =
          W[(size_t)(m0 + am) * sWm + (size_t)(k0 + ak + u) * sWk];
#pragma unroll
    for (int u = 0; u < 4; ++u)
      Bs[bk + u][bn] = (bc >= 0) ? Xb[(size_t)(k0 + bk + u) * SEQ + bc] : 0.0f;
    __syncthreads();
#pragma unroll
    for (int kk = 0; kk < 16; ++kk) {
      const float4 av = *reinterpret_cast<const float4*>(&As[kk][ty * 4]);
      const float4 bv = *reinterpret_cast<const float4*>(&Bs[kk][tx * 4]);
      const float a0[4] = {av.x, av.y, av.z, av.w};
      const float b0[4] = {bv.x, bv.y, bv.z, bv.w};
#pragma unroll
      for (int i = 0; i < 4; ++i)
#pragma unroll
        for (int j = 0; j < 4; ++j)
          acc[i][j] = fmaf(a0[i], b0[j], acc[i][j]);
    }
    __syncthreads();
  }

#pragma unroll
  for (int i = 0; i < 4; ++i) {
    float* cp = Cb + (size_t)(m0 + ty * 4 + i) * SEQ + (n0 + tx * 4);
    if (accumulate) {
#pragma unroll
      for (int j = 0; j < 4; ++j) cp[j] += acc[i][j];
    } else {
      *reinterpret_cast<float4*>(cp) =
          make_float4(acc[i][0], acc[i][1], acc[i][2], acc[i][3]);
    }
  }
}

// In-place: relu -> mean-center over S -> x * sqrt(S) / (||x|| + eps)
__global__ __launch_bounds__(256) void act_norm_kernel(float* __restrict__ data)
{
  __shared__ float red[8];
  float* __restrict__ r = data + (size_t)blockIdx.x * SEQ;
  const int tid = threadIdx.x;

  float v[8];
  float lsum = 0.f;
#pragma unroll
  for (int u = 0; u < 8; ++u) {
    float t = r[tid + u * 256];
    t = t > 0.f ? t : 0.f;
    v[u] = t;
    lsum += t;
  }
  lsum = wave_reduce_add(lsum);
  if ((tid & 63) == 0) red[tid >> 6] = lsum;
  __syncthreads();
  const float mean = (red[0] + red[1] + red[2] + red[3]) * (1.0f / SEQ);
  float lss = 0.f;
#pragma unroll
  for (int u = 0; u < 8; ++u) {
    v[u] -= mean;
    lss += v[u] * v[u];
  }
  lss = wave_reduce_add(lss);
  if ((tid & 63) == 0) red[4 + (tid >> 6)] = lss;
  __syncthreads();
  const float ss = red[4] + red[5] + red[6] + red[7];
  const float scl = sqrtf((float)SEQ) / (sqrtf(ss) + EPSV);
#pragma unroll
  for (int u = 0; u < 8; ++u)
    r[tid + u * 256] = v[u] * scl;
}

// depth[b,f,s] <- cumsum_f(depth)/divisor[f,s]*scl[b,f,s] + shf[b,f,s]
__global__ __launch_bounds__(256) void combine_kernel(
    float* __restrict__ depth, const float* __restrict__ divisor,
    const float* __restrict__ scl, const float* __restrict__ shf)
{
  const int b = blockIdx.y;
  const int s = blockIdx.x * 256 + threadIdx.x;
  float acc = 0.f;
  for (int f = 0; f < FCH; ++f) {
    const size_t idx = ((size_t)b * FCH + f) * SEQ + s;
    const size_t dix = (size_t)f * SEQ + s;
    acc += depth[idx];
    depth[idx] = acc / divisor[dix] * scl[idx] + shf[idx];
  }
}

// out = inp + act_norm(comb), row-wise over S
__global__ __launch_bounds__(256) void final_norm_kernel(
    const float* __restrict__ comb, const float* __restrict__ inp,
    float* __restrict__ out)
{
  __shared__ float red[8];
  const size_t base = (size_t)blockIdx.x * SEQ;
  const int tid = threadIdx.x;

  float v[8];
  float lsum = 0.f;
#pragma unroll
  for (int u = 0; u < 8; ++u) {
    float t = comb[base + tid + u * 256];
    t = t > 0.f ? t : 0.f;
    v[u] = t;
    lsum += t;
  }
  lsum = wave_reduce_add(lsum);
  if ((tid & 63) == 0) red[tid >> 6] = lsum;
  __syncthreads();
  const float mean = (red[0] + red[1] + red[2] + red[3]) * (1.0f / SEQ);
  float lss = 0.f;
#pragma unroll
  for (int u = 0; u < 8; ++u) {
    v[u] -= mean;
    lss += v[u] * v[u];
  }
  lss = wave_reduce_add(lss);
  if ((tid & 63) == 0) red[4 + (tid >> 6)] = lss;
  __syncthreads();
  const float ss = red[4] + red[5] + red[6] + red[7];
  const float scl = sqrtf((float)SEQ) / (sqrtf(ss) + EPSV);
#pragma unroll
  for (int u = 0; u < 8; ++u)
    out[base + tid + u * 256] = inp[base + tid + u * 256] + v[u] * scl;
}

extern "C" void kernel_launch(void* const* d_in, const int* in_sizes, int n_in,
                              void* d_out, int out_size, void* d_ws, size_t ws_size,
                              hipStream_t stream)
{
  const float* inp     = (const float*)d_in[0];
  const float* pos     = (const float*)d_in[1];
  const float* divisor = (const float*)d_in[2];
  const float* w_[9];
  for (int i = 0; i < 9; ++i) w_[i] = (const float*)d_in[3 + i];
  // w_[0..2]=dw0,dw1,dw2  w_[3..5]=sw*  w_[6..8]=hw*
  float* out = (float*)d_out;

  // workspace layout (floats): X[B*F*S] T0[B*I*S] T1[B*I*S] D[B*F*S]  (~201 MB)
  float* X  = (float*)d_ws;
  float* T0 = X  + (size_t)BSZ * FCH * SEQ;
  float* T1 = T0 + (size_t)BSZ * ICH * SEQ;
  float* D  = T1 + (size_t)BSZ * ICH * SEQ;

  add_pos_kernel<<<4096, 256, 0, stream>>>(inp, pos, X);

  auto run_ff = [&](const float* w0, const float* w1, const float* w2,
                    float* dst) {
    // conv0: [I,F] @ X  -> T0, then act_norm in place
    gemm_shift_kernel<<<dim3(SEQ / 64, ICH / 64, BSZ), 256, 0, stream>>>(
        w0, FCH, 1, X, T0, ICH, FCH, 0, 0);
    act_norm_kernel<<<BSZ * ICH, 256, 0, stream>>>(T0);
    // conv1: causal K=5 as 5 shifted GEMMs accumulated into T1
    for (int k = 0; k < KW; ++k)
      gemm_shift_kernel<<<dim3(SEQ / 64, ICH / 64, BSZ), 256, 0, stream>>>(
          w1 + k, ICH * KW, KW, T0, T1, ICH, ICH, k - (KW - 1),
          k > 0 ? 1 : 0);
    act_norm_kernel<<<BSZ * ICH, 256, 0, stream>>>(T1);
    // conv2: [F,I] @ T1 -> dst
    gemm_shift_kernel<<<dim3(SEQ / 64, FCH / 64, BSZ), 256, 0, stream>>>(
        w2, ICH, 1, T1, dst, FCH, ICH, 0, 0);
  };

  run_ff(w_[0], w_[1], w_[2], D);    // depth -> D
  run_ff(w_[6], w_[7], w_[8], out);  // shift -> out (scratch; rewritten below)
  run_ff(w_[3], w_[4], w_[5], X);    // scale -> X (X dead after its conv0; MUST run last)

  combine_kernel<<<dim3(SEQ / 256, BSZ), 256, 0, stream>>>(D, divisor, X, out);
  final_norm_kernel<<<BSZ * FCH, 256, 0, stream>>>(D, inp, out);
}

// Round 2
// 3092.168 us; speedup vs baseline: 7.7618x; 7.7618x over previous
//
#include <hip/hip_runtime.h>
#include <math.h>

#define BSZ 4
#define FCH 1024
#define SEQ 2048
#define ICH 2048
#define KW  5
#define EPSV 1e-5f
#define RPAD 2244  // 4 front zero-pad + 2048 rows + 192 stage-overrun slack

typedef __attribute__((ext_vector_type(8))) short bf16x8;
typedef __attribute__((ext_vector_type(4))) float f32x4;
typedef __attribute__((ext_vector_type(4))) unsigned short us4;

__device__ __forceinline__ unsigned short f2bf(float f) {
  union { float f; unsigned u; } v; v.f = f;
  unsigned r = v.u + 0x7fff + ((v.u >> 16) & 1);  // round-to-nearest-even
  return (unsigned short)(r >> 16);
}

__device__ __forceinline__ void gload_lds16(const void* g, void* l) {
  __builtin_amdgcn_global_load_lds(
      (const __attribute__((address_space(1))) void*)g,
      (__attribute__((address_space(3))) void*)l, 16, 0, 0);
}

// ---------------- input transpose + pos add:  [b][f][s] -> bf16 [b][4+s][f]
__global__ __launch_bounds__(256) void addpos_T_kernel(
    const float* __restrict__ inp, const float* __restrict__ pos,
    unsigned short* __restrict__ X)
{
  __shared__ float t[64][65];
  const int s0 = blockIdx.x * 64, f0 = blockIdx.y * 64, b = blockIdx.z;
  const int a = threadIdx.x & 63, g = threadIdx.x >> 6;
  const float* ib = inp + (size_t)b * FCH * SEQ;
#pragma unroll
  for (int i = 0; i < 16; ++i) {
    const size_t o = (size_t)(f0 + g + i * 4) * SEQ + s0 + a;
    t[a][g + i * 4] = ib[o] + pos[o];
  }
  __syncthreads();
#pragma unroll
  for (int i = 0; i < 16; ++i)
    X[(size_t)b * RPAD * FCH + (size_t)(4 + s0 + g + i * 4) * FCH + f0 + a] =
        f2bf(t[g + i * 4][a]);
}

// zero the 4 leading pad rows of Xbf per batch
__global__ __launch_bounds__(256) void zero_xpad_kernel(unsigned short* __restrict__ X)
{
  const int i = blockIdx.x * 256 + threadIdx.x;  // < BSZ*4*FCH
  const int b = i / (4 * FCH);
  const int r = i % (4 * FCH);
  X[(size_t)b * RPAD * FCH + r] = 0;
}

// divisor [f][s] -> divT [s][f] fp32
__global__ __launch_bounds__(256) void transpose_div_kernel(
    const float* __restrict__ D, float* __restrict__ O)
{
  __shared__ float t[64][65];
  const int s0 = blockIdx.x * 64, f0 = blockIdx.y * 64;
  const int a = threadIdx.x & 63, g = threadIdx.x >> 6;
#pragma unroll
  for (int i = 0; i < 16; ++i)
    t[a][g + i * 4] = D[(size_t)(f0 + g + i * 4) * SEQ + s0 + a];
  __syncthreads();
#pragma unroll
  for (int i = 0; i < 16; ++i)
    O[(size_t)(s0 + g + i * 4) * FCH + f0 + a] = t[g + i * 4][a];
}

// ---------------- weight converts
__global__ __launch_bounds__(256) void cast_bf_kernel(
    const float* __restrict__ I, unsigned short* __restrict__ O)
{
  const size_t i = ((size_t)blockIdx.x * 256 + threadIdx.x) * 4;
  const float4 v = *(const float4*)(I + i);
  us4 o; o.x = f2bf(v.x); o.y = f2bf(v.y); o.z = f2bf(v.z); o.w = f2bf(v.w);
  *(us4*)(O + i) = o;
}

// W1 [m][c][k] fp32 -> O [k][m][c] bf16
__global__ __launch_bounds__(256) void cast_w1_kernel(
    const float* __restrict__ W, unsigned short* __restrict__ O)
{
  const int c = blockIdx.x * 256 + threadIdx.x;
  const int m = blockIdx.y;
  const float* s = W + ((size_t)m * ICH + c) * KW;
#pragma unroll
  for (int k = 0; k < KW; ++k)
    O[((size_t)k * ICH + m) * ICH + c] = f2bf(s[k]);
}

// ---------------- fused multi-tap MFMA GEMM
// C[b][s][m] = sum_t sum_c A[b][4+s+t-(NTAPS-1)][c] * W[t][m][c]
// A is bf16 [BSZ][RPAD][K] (rows 0..3 zero), W bf16 [NTAPS][M][K], C fp32.
// 128(s) x 128(m) tile, BK=32, 4 waves each 64x64, single-buffer 2-barrier loop.
template <int NTAPS>
__global__ __launch_bounds__(256) void gemm_mfma_kernel(
    const unsigned short* __restrict__ A, const unsigned short* __restrict__ W,
    float* __restrict__ C, int M, int K)
{
  __shared__ __align__(16) char lds[12288 + NTAPS * 8192];
  const int tid = threadIdx.x;
  const int wv = tid >> 6;
  const int ln = tid & 63;
  const int s0 = blockIdx.x * 128;
  const int m0 = blockIdx.y * 128;
  const int b  = blockIdx.z;

  const char* Ab = (const char*)(A + (size_t)b * RPAD * K);
  const char* Wb = (const char*)W;
  const size_t Arow = (size_t)K * 2;

  const int wr = wv >> 1, wc = wv & 1;
  const int l15 = ln & 15;
  const int lhi = ln >> 4;
  const int chunk = lhi * 16;

  f32x4 acc[4][4] = {};

  for (int k0 = 0; k0 < K; k0 += 32) {
    // stage A: LDS rows 0..191 <- padded rows s0..s0+191, 64B (32 bf16) each
#pragma unroll
    for (int q = 0; q < 3; ++q) {
      const int L = q * 4096 + tid * 16;
      gload_lds16(Ab + (size_t)(s0 + (L >> 6)) * Arow + (size_t)k0 * 2 + (L & 63),
                  lds + q * 4096 + wv * 1024);
    }
    // stage B: per tap rows m0..m0+127
#pragma unroll
    for (int t = 0; t < NTAPS; ++t) {
#pragma unroll
      for (int q = 0; q < 2; ++q) {
        const int L = q * 4096 + tid * 16;
        gload_lds16(Wb + ((size_t)t * M * K + (size_t)(m0 + (L >> 6)) * K + k0) * 2 + (L & 63),
                    lds + 12288 + t * 8192 + q * 4096 + wv * 1024);
      }
    }
    asm volatile("s_waitcnt vmcnt(0)" ::: "memory");
    __syncthreads();

#pragma unroll
    for (int t = 0; t < NTAPS; ++t) {
      const int roff = (NTAPS == 1) ? 4 : t;  // A lds-row offset for tap shift
      bf16x8 af[4], bfr[4];
#pragma unroll
      for (int i = 0; i < 4; ++i) {
        const int r = wr * 64 + i * 16 + l15 + roff;
        af[i] = *(const bf16x8*)(lds + r * 64 + chunk);
      }
#pragma unroll
      for (int j = 0; j < 4; ++j) {
        const int r = wc * 64 + j * 16 + l15;
        bfr[j] = *(const bf16x8*)(lds + 12288 + t * 8192 + r * 64 + chunk);
      }
#pragma unroll
      for (int i = 0; i < 4; ++i)
#pragma unroll
        for (int j = 0; j < 4; ++j)
          acc[i][j] = __builtin_amdgcn_mfma_f32_16x16x32_bf16(af[i], bfr[j],
                                                              acc[i][j], 0, 0, 0);
    }
    __syncthreads();
  }

  float* Cb = C + (size_t)b * SEQ * M;
#pragma unroll
  for (int i = 0; i < 4; ++i) {
    const int sbase = s0 + wr * 64 + i * 16 + lhi * 4;
#pragma unroll
    for (int j = 0; j < 4; ++j) {
      const int m = m0 + wc * 64 + j * 16 + l15;
#pragma unroll
      for (int r = 0; r < 4; ++r)
        Cb[(size_t)(sbase + r) * M + m] = acc[i][j][r];
    }
  }
}

// ---------------- act_norm over s (column-wise in [s][m]), fp32 -> padded bf16
__global__ __launch_bounds__(256) void act_norm_col_kernel(
    const float* __restrict__ Cf, unsigned short* __restrict__ Ob, int M)
{
  const int b = blockIdx.y;
  const int mi = threadIdx.x & 63;
  const int sg = threadIdx.x >> 6;
  const int m = blockIdx.x * 64 + mi;
  const float* src = Cf + (size_t)b * SEQ * M + m;
  float sum = 0.f, sq = 0.f;
  for (int s = sg; s < SEQ; s += 4) {
    const float x = fmaxf(src[(size_t)s * M], 0.f);
    sum += x; sq += x * x;
  }
  __shared__ float rs[4][64], rq[4][64];
  rs[sg][mi] = sum; rq[sg][mi] = sq;
  __syncthreads();
  const float S1 = rs[0][mi] + rs[1][mi] + rs[2][mi] + rs[3][mi];
  const float S2 = rq[0][mi] + rq[1][mi] + rq[2][mi] + rq[3][mi];
  const float mean = S1 * (1.f / SEQ);
  const float ss = fmaxf(S2 - SEQ * mean * mean, 0.f);
  const float scl = sqrtf((float)SEQ) / (sqrtf(ss) + EPSV);
  unsigned short* dst = Ob + (size_t)b * RPAD * M + m;
  if (sg == 0) {
#pragma unroll
    for (int r = 0; r < 4; ++r) dst[(size_t)r * M] = 0;  // causal zero pad
  }
  for (int s = sg; s < SEQ; s += 4)
    dst[(size_t)(4 + s) * M] = f2bf((fmaxf(src[(size_t)s * M], 0.f) - mean) * scl);
}

// ---------------- cumsum over f (fast dim) + divide/scale/shift, in place on Dp
__global__ __launch_bounds__(256) void combine_kernel(
    float* __restrict__ Dp, const float* __restrict__ divT,
    const float* __restrict__ Sc, const float* __restrict__ Sh)
{
  const int row = blockIdx.x * 4 + (threadIdx.x >> 6);  // (b,s) flat
  const int b = row >> 11, s = row & 2047;
  const int ln = threadIdx.x & 63;
  const size_t base = ((size_t)b * SEQ + s) * FCH;
  const float* dv = divT + (size_t)s * FCH;
  float carry = 0.f;
  for (int c0 = 0; c0 < FCH; c0 += 64) {
    float x = Dp[base + c0 + ln];
#pragma unroll
    for (int d = 1; d < 64; d <<= 1) {
      const float t = __shfl_up(x, d, 64);
      if (ln >= d) x += t;
    }
    x += carry;
    carry = __shfl(x, 63, 64);
    Dp[base + c0 + ln] = x / dv[c0 + ln] * Sc[base + c0 + ln] + Sh[base + c0 + ln];
  }
}

// ---------------- final: out[b][f][s] = inp + act_norm_S(comb[b][s][f])
__global__ __launch_bounds__(256) void final_kernel(
    const float* __restrict__ Cb, const float* __restrict__ inp,
    float* __restrict__ out)
{
  const int b = blockIdx.y, f0 = blockIdx.x * 64;
  const int fi = threadIdx.x & 63, sg = threadIdx.x >> 6;
  const float* src = Cb + (size_t)b * SEQ * FCH + f0 + fi;
  float sum = 0.f, sq = 0.f;
  for (int s = sg; s < SEQ; s += 4) {
    const float x = fmaxf(src[(size_t)s * FCH], 0.f);
    sum += x; sq += x * x;
  }
  __shared__ float rs[4][64], rq[4][64];
  __shared__ float tile[64][65];
  rs[sg][fi] = sum; rq[sg][fi] = sq;
  __syncthreads();
  const float S1 = rs[0][fi] + rs[1][fi] + rs[2][fi] + rs[3][fi];
  const float S2 = rq[0][fi] + rq[1][fi] + rq[2][fi] + rq[3][fi];
  const float mean = S1 * (1.f / SEQ);
  const float ss = fmaxf(S2 - SEQ * mean * mean, 0.f);
  const float scl = sqrtf((float)SEQ) / (sqrtf(ss) + EPSV);

  for (int s0 = 0; s0 < SEQ; s0 += 64) {
#pragma unroll
    for (int i = 0; i < 16; ++i) {
      const int sl = sg + i * 4;
      const float x =
          fmaxf(Cb[(size_t)b * SEQ * FCH + (size_t)(s0 + sl) * FCH + f0 + fi], 0.f);
      tile[sl][fi] = (x - mean) * scl;
    }
    __syncthreads();
#pragma unroll
    for (int i = 0; i < 16; ++i) {
      const int fl = sg + i * 4, sl = fi;
      const size_t o = ((size_t)b * FCH + f0 + fl) * SEQ + s0 + sl;
      out[o] = inp[o] + tile[sl][fl];
    }
    __syncthreads();
  }
}

extern "C" void kernel_launch(void* const* d_in, const int* in_sizes, int n_in,
                              void* d_out, int out_size, void* d_ws, size_t ws_size,
                              hipStream_t stream)
{
  const float* inp     = (const float*)d_in[0];
  const float* pos     = (const float*)d_in[1];
  const float* divisor = (const float*)d_in[2];
  const float* w_[9];
  for (int i = 0; i < 9; ++i) w_[i] = (const float*)d_in[3 + i];
  float* out = (float*)d_out;

  // workspace layout (~282 MB)
  char* p = (char*)d_ws;
  float*          divT = (float*)p;          p += (size_t)SEQ * FCH * 4;
  unsigned short* Xbf  = (unsigned short*)p; p += (size_t)BSZ * RPAD * FCH * 2;
  unsigned short* T0b  = (unsigned short*)p; p += (size_t)BSZ * RPAD * ICH * 2;
  float*          Cf   = (float*)p;          p += (size_t)BSZ * SEQ * ICH * 4;
  float*          Df   = (float*)p;          p += (size_t)BSZ * SEQ * FCH * 4;
  float*          Sf   = (float*)p;          p += (size_t)BSZ * SEQ * FCH * 4;
  float*          Hf   = (float*)p;          p += (size_t)BSZ * SEQ * FCH * 4;
  unsigned short* w0b  = (unsigned short*)p; p += (size_t)ICH * FCH * 2;
  unsigned short* w1b  = (unsigned short*)p; p += (size_t)KW * ICH * ICH * 2;
  unsigned short* w2b  = (unsigned short*)p; p += (size_t)FCH * ICH * 2;

  zero_xpad_kernel<<<BSZ * 4 * FCH / 256, 256, 0, stream>>>(Xbf);
  addpos_T_kernel<<<dim3(SEQ / 64, FCH / 64, BSZ), 256, 0, stream>>>(inp, pos, Xbf);
  transpose_div_kernel<<<dim3(SEQ / 64, FCH / 64), 256, 0, stream>>>(divisor, divT);

  auto run_ff = [&](const float* w0, const float* w1, const float* w2, float* dst) {
    cast_bf_kernel<<<(ICH * FCH) / 1024, 256, 0, stream>>>(w0, w0b);
    cast_w1_kernel<<<dim3(ICH / 256, ICH), 256, 0, stream>>>(w1, w1b);
    cast_bf_kernel<<<(FCH * ICH) / 1024, 256, 0, stream>>>(w2, w2b);
    // conv0: M=ICH, K=FCH
    gemm_mfma_kernel<1><<<dim3(SEQ / 128, ICH / 128, BSZ), 256, 0, stream>>>(
        Xbf, w0b, Cf, ICH, FCH);
    act_norm_col_kernel<<<dim3(ICH / 64, BSZ), 256, 0, stream>>>(Cf, T0b, ICH);
    // conv1: 5 fused causal taps, M=ICH, K=ICH
    gemm_mfma_kernel<5><<<dim3(SEQ / 128, ICH / 128, BSZ), 256, 0, stream>>>(
        T0b, w1b, Cf, ICH, ICH);
    act_norm_col_kernel<<<dim3(ICH / 64, BSZ), 256, 0, stream>>>(Cf, T0b, ICH);
    // conv2: M=FCH, K=ICH
    gemm_mfma_kernel<1><<<dim3(SEQ / 128, FCH / 128, BSZ), 256, 0, stream>>>(
        T0b, w2b, dst, FCH, ICH);
  };

  run_ff(w_[0], w_[1], w_[2], Df);  // depth
  run_ff(w_[3], w_[4], w_[5], Sf);  // scale
  run_ff(w_[6], w_[7], w_[8], Hf);  // shift

  combine_kernel<<<(BSZ * SEQ) / 4, 256, 0, stream>>>(Df, divT, Sf, Hf);
  final_kernel<<<dim3(FCH / 64, BSZ), 256, 0, stream>>>(Df, inp, out);
}

// Round 3
// 1713.768 us; speedup vs baseline: 14.0046x; 1.8043x over previous
//
#include <hip/hip_runtime.h>
#include <math.h>

#define BSZ 4
#define FCH 1024
#define SEQ 2048
#define ICH 2048
#define KW  5
#define EPSV 1e-5f
#define RPAD 2244  // 4 front zero-pad + 2048 rows + 192 stage-overrun slack
#define NCHUNK 16  // SEQ/128 row chunks for column reductions

typedef __attribute__((ext_vector_type(8))) short bf16x8;
typedef __attribute__((ext_vector_type(4))) float f32x4;
typedef __attribute__((ext_vector_type(4))) unsigned short us4;

__device__ __forceinline__ unsigned short f2bf(float f) {
  union { float f; unsigned u; } v; v.f = f;
  unsigned r = v.u + 0x7fff + ((v.u >> 16) & 1);  // round-to-nearest-even
  return (unsigned short)(r >> 16);
}

__device__ __forceinline__ void gload_lds16(const void* g, void* l) {
  __builtin_amdgcn_global_load_lds(
      (const __attribute__((address_space(1))) void*)g,
      (__attribute__((address_space(3))) void*)l, 16, 0, 0);
}

// ---------------- input transpose + pos add:  [b][f][s] -> bf16 [b][4+s][f]
__global__ __launch_bounds__(256) void addpos_T_kernel(
    const float* __restrict__ inp, const float* __restrict__ pos,
    unsigned short* __restrict__ X)
{
  __shared__ float t[64][65];
  const int s0 = blockIdx.x * 64, f0 = blockIdx.y * 64, b = blockIdx.z;
  const int a = threadIdx.x & 63, g = threadIdx.x >> 6;
  const float* ib = inp + (size_t)b * FCH * SEQ;
#pragma unroll
  for (int i = 0; i < 16; ++i) {
    const size_t o = (size_t)(f0 + g + i * 4) * SEQ + s0 + a;
    t[a][g + i * 4] = ib[o] + pos[o];
  }
  __syncthreads();
#pragma unroll
  for (int i = 0; i < 16; ++i)
    X[(size_t)b * RPAD * FCH + (size_t)(4 + s0 + g + i * 4) * FCH + f0 + a] =
        f2bf(t[g + i * 4][a]);
}

// zero the 4 leading pad rows of Xbf per batch
__global__ __launch_bounds__(256) void zero_xpad_kernel(unsigned short* __restrict__ X)
{
  const int i = blockIdx.x * 256 + threadIdx.x;  // < BSZ*4*FCH
  const int b = i / (4 * FCH);
  const int r = i % (4 * FCH);
  X[(size_t)b * RPAD * FCH + r] = 0;
}

// divisor [f][s] -> divT [s][f] fp32
__global__ __launch_bounds__(256) void transpose_div_kernel(
    const float* __restrict__ D, float* __restrict__ O)
{
  __shared__ float t[64][65];
  const int s0 = blockIdx.x * 64, f0 = blockIdx.y * 64;
  const int a = threadIdx.x & 63, g = threadIdx.x >> 6;
#pragma unroll
  for (int i = 0; i < 16; ++i)
    t[a][g + i * 4] = D[(size_t)(f0 + g + i * 4) * SEQ + s0 + a];
  __syncthreads();
#pragma unroll
  for (int i = 0; i < 16; ++i)
    O[(size_t)(s0 + g + i * 4) * FCH + f0 + a] = t[g + i * 4][a];
}

// ---------------- weight converts
__global__ __launch_bounds__(256) void cast_bf_kernel(
    const float* __restrict__ I, unsigned short* __restrict__ O)
{
  const size_t i = ((size_t)blockIdx.x * 256 + threadIdx.x) * 4;
  const float4 v = *(const float4*)(I + i);
  us4 o; o.x = f2bf(v.x); o.y = f2bf(v.y); o.z = f2bf(v.z); o.w = f2bf(v.w);
  *(us4*)(O + i) = o;
}

// W1 [m][c][k] fp32 -> O [k][m][c] bf16
__global__ __launch_bounds__(256) void cast_w1_kernel(
    const float* __restrict__ W, unsigned short* __restrict__ O)
{
  const int c = blockIdx.x * 256 + threadIdx.x;
  const int m = blockIdx.y;
  const float* s = W + ((size_t)m * ICH + c) * KW;
#pragma unroll
  for (int k = 0; k < KW; ++k)
    O[((size_t)k * ICH + m) * ICH + c] = f2bf(s[k]);
}

// ---------------- fused multi-tap MFMA GEMM
// C[b][s][m] = sum_t sum_c A[b][4+s+t-(NTAPS-1)][c] * W[t][m][c]
// A is bf16 [BSZ][RPAD][K] (rows 0..3 zero), W bf16 [NTAPS][M][K], C fp32.
// 128(s) x 128(m) tile, BK=32, 4 waves each 64x64, single-buffer 2-barrier loop.
template <int NTAPS>
__global__ __launch_bounds__(256) void gemm_mfma_kernel(
    const unsigned short* __restrict__ A, const unsigned short* __restrict__ W,
    float* __restrict__ C, int M, int K)
{
  __shared__ __align__(16) char lds[12288 + NTAPS * 8192];
  const int tid = threadIdx.x;
  const int wv = tid >> 6;
  const int ln = tid & 63;
  const int s0 = blockIdx.x * 128;
  const int m0 = blockIdx.y * 128;
  const int b  = blockIdx.z;

  const char* Ab = (const char*)(A + (size_t)b * RPAD * K);
  const char* Wb = (const char*)W;
  const size_t Arow = (size_t)K * 2;

  const int wr = wv >> 1, wc = wv & 1;
  const int l15 = ln & 15;
  const int lhi = ln >> 4;
  const int chunk = lhi * 16;

  f32x4 acc[4][4] = {};

  for (int k0 = 0; k0 < K; k0 += 32) {
    // stage A: LDS rows 0..191 <- padded rows s0..s0+191, 64B (32 bf16) each
#pragma unroll
    for (int q = 0; q < 3; ++q) {
      const int L = q * 4096 + tid * 16;
      gload_lds16(Ab + (size_t)(s0 + (L >> 6)) * Arow + (size_t)k0 * 2 + (L & 63),
                  lds + q * 4096 + wv * 1024);
    }
    // stage B: per tap rows m0..m0+127
#pragma unroll
    for (int t = 0; t < NTAPS; ++t) {
#pragma unroll
      for (int q = 0; q < 2; ++q) {
        const int L = q * 4096 + tid * 16;
        gload_lds16(Wb + ((size_t)t * M * K + (size_t)(m0 + (L >> 6)) * K + k0) * 2 + (L & 63),
                    lds + 12288 + t * 8192 + q * 4096 + wv * 1024);
      }
    }
    asm volatile("s_waitcnt vmcnt(0)" ::: "memory");
    __syncthreads();

#pragma unroll
    for (int t = 0; t < NTAPS; ++t) {
      const int roff = (NTAPS == 1) ? 4 : t;  // A lds-row offset for tap shift
      bf16x8 af[4], bfr[4];
#pragma unroll
      for (int i = 0; i < 4; ++i) {
        const int r = wr * 64 + i * 16 + l15 + roff;
        af[i] = *(const bf16x8*)(lds + r * 64 + chunk);
      }
#pragma unroll
      for (int j = 0; j < 4; ++j) {
        const int r = wc * 64 + j * 16 + l15;
        bfr[j] = *(const bf16x8*)(lds + 12288 + t * 8192 + r * 64 + chunk);
      }
#pragma unroll
      for (int i = 0; i < 4; ++i)
#pragma unroll
        for (int j = 0; j < 4; ++j)
          acc[i][j] = __builtin_amdgcn_mfma_f32_16x16x32_bf16(af[i], bfr[j],
                                                              acc[i][j], 0, 0, 0);
    }
    __syncthreads();
  }

  float* Cb = C + (size_t)b * SEQ * M;
#pragma unroll
  for (int i = 0; i < 4; ++i) {
    const int sbase = s0 + wr * 64 + i * 16 + lhi * 4;
#pragma unroll
    for (int j = 0; j < 4; ++j) {
      const int m = m0 + wc * 64 + j * 16 + l15;
#pragma unroll
      for (int r = 0; r < 4; ++r)
        Cb[(size_t)(sbase + r) * M + m] = acc[i][j][r];
    }
  }
}

// ---------------- column act_norm, split into 3 parallel dispatches ----------
// colred: partial sum/sumsq of relu(x) over 128-row chunks. P [b][chunk][M]
__global__ __launch_bounds__(256) void colred_kernel(
    const float* __restrict__ Cf, float* __restrict__ P1,
    float* __restrict__ P2, int M)
{
  const int b = blockIdx.z;
  const int mi = threadIdx.x & 63;
  const int sg = threadIdx.x >> 6;
  const int m = blockIdx.x * 64 + mi;
  const int s0 = blockIdx.y * 128;
  const float* src = Cf + ((size_t)b * SEQ + s0) * M + m;
  float sum = 0.f, sq = 0.f;
  for (int s = sg; s < 128; s += 4) {
    const float x = fmaxf(src[(size_t)s * M], 0.f);
    sum += x; sq += x * x;
  }
  __shared__ float rs[4][64], rq[4][64];
  rs[sg][mi] = sum; rq[sg][mi] = sq;
  __syncthreads();
  if (sg == 0) {
    const size_t o = ((size_t)b * NCHUNK + blockIdx.y) * M + m;
    P1[o] = rs[0][mi] + rs[1][mi] + rs[2][mi] + rs[3][mi];
    P2[o] = rq[0][mi] + rq[1][mi] + rq[2][mi] + rq[3][mi];
  }
}

// colfin: mean/scale per (b,m).  MS [b][2][M]
__global__ __launch_bounds__(256) void colfin_kernel(
    const float* __restrict__ P1, const float* __restrict__ P2,
    float* __restrict__ MS, int M)
{
  const int i = blockIdx.x * 256 + threadIdx.x;  // < BSZ*M
  const int b = i / M, m = i % M;
  float S1 = 0.f, S2 = 0.f;
#pragma unroll
  for (int c = 0; c < NCHUNK; ++c) {
    S1 += P1[((size_t)b * NCHUNK + c) * M + m];
    S2 += P2[((size_t)b * NCHUNK + c) * M + m];
  }
  const float mean = S1 * (1.f / SEQ);
  const float ss = fmaxf(S2 - SEQ * mean * mean, 0.f);
  const float scl = sqrtf((float)SEQ) / (sqrtf(ss) + EPSV);
  MS[((size_t)b * 2 + 0) * M + m] = mean;
  MS[((size_t)b * 2 + 1) * M + m] = scl;
}

// colapply: normalized relu -> bf16 padded activation buffer
__global__ __launch_bounds__(256) void colapply_kernel(
    const float* __restrict__ Cf, const float* __restrict__ MS,
    unsigned short* __restrict__ Ob, int M)
{
  const int b = blockIdx.z;
  const int mi = threadIdx.x & 63;
  const int sg = threadIdx.x >> 6;
  const int m = blockIdx.x * 64 + mi;
  const int s0 = blockIdx.y * 128;
  const float mean = MS[((size_t)b * 2 + 0) * M + m];
  const float scl  = MS[((size_t)b * 2 + 1) * M + m];
  const float* src = Cf + ((size_t)b * SEQ + s0) * M + m;
  unsigned short* dst = Ob + ((size_t)b * RPAD + 4 + s0) * M + m;
  if (blockIdx.y == 0 && sg == 0) {
#pragma unroll
    for (int r = 0; r < 4; ++r) Ob[((size_t)b * RPAD + r) * M + m] = 0;
  }
  for (int s = sg; s < 128; s += 4)
    dst[(size_t)s * M] = f2bf((fmaxf(src[(size_t)s * M], 0.f) - mean) * scl);
}

// ---------------- cumsum over f (fast dim) + divide/scale/shift, in place on Dp
__global__ __launch_bounds__(256) void combine_kernel(
    float* __restrict__ Dp, const float* __restrict__ divT,
    const float* __restrict__ Sc, const float* __restrict__ Sh)
{
  const int row = blockIdx.x * 4 + (threadIdx.x >> 6);  // (b,s) flat
  const int b = row >> 11, s = row & 2047;
  const int ln = threadIdx.x & 63;
  const size_t base = ((size_t)b * SEQ + s) * FCH;
  const float* dv = divT + (size_t)s * FCH;
  float carry = 0.f;
  for (int c0 = 0; c0 < FCH; c0 += 64) {
    float x = Dp[base + c0 + ln];
#pragma unroll
    for (int d = 1; d < 64; d <<= 1) {
      const float t = __shfl_up(x, d, 64);
      if (ln >= d) x += t;
    }
    x += carry;
    carry = __shfl(x, 63, 64);
    Dp[base + c0 + ln] = x / dv[c0 + ln] * Sc[base + c0 + ln] + Sh[base + c0 + ln];
  }
}

// ---------------- final apply: out[b][f][s] = inp + (relu(Df)-mean)*scl, transposed
__global__ __launch_bounds__(256) void final_apply_kernel(
    const float* __restrict__ Df, const float* __restrict__ MS,
    const float* __restrict__ inp, float* __restrict__ out)
{
  __shared__ float tile[64][65];
  const int b = blockIdx.z;
  const int s0 = blockIdx.x * 64, f0 = blockIdx.y * 64;
  const int a = threadIdx.x & 63, g = threadIdx.x >> 6;
  const float mean = MS[((size_t)b * 2 + 0) * FCH + f0 + a];
  const float scl  = MS[((size_t)b * 2 + 1) * FCH + f0 + a];
#pragma unroll
  for (int i = 0; i < 16; ++i) {
    const int s = g + i * 4;
    const float x = fmaxf(Df[((size_t)b * SEQ + s0 + s) * FCH + f0 + a], 0.f);
    tile[s][a] = (x - mean) * scl;
  }
  __syncthreads();
#pragma unroll
  for (int i = 0; i < 16; ++i) {
    const int f = g + i * 4;
    const size_t o = ((size_t)b * FCH + f0 + f) * SEQ + s0 + a;
    out[o] = inp[o] + tile[a][f];
  }
}

extern "C" void kernel_launch(void* const* d_in, const int* in_sizes, int n_in,
                              void* d_out, int out_size, void* d_ws, size_t ws_size,
                              hipStream_t stream)
{
  const float* inp     = (const float*)d_in[0];
  const float* pos     = (const float*)d_in[1];
  const float* divisor = (const float*)d_in[2];
  const float* w_[9];
  for (int i = 0; i < 9; ++i) w_[i] = (const float*)d_in[3 + i];
  float* out = (float*)d_out;

  // workspace layout (~283 MB)
  char* p = (char*)d_ws;
  float*          divT = (float*)p;          p += (size_t)SEQ * FCH * 4;
  unsigned short* Xbf  = (unsigned short*)p; p += (size_t)BSZ * RPAD * FCH * 2;
  unsigned short* T0b  = (unsigned short*)p; p += (size_t)BSZ * RPAD * ICH * 2;
  float*          Cf   = (float*)p;          p += (size_t)BSZ * SEQ * ICH * 4;
  float*          Df   = (float*)p;          p += (size_t)BSZ * SEQ * FCH * 4;
  float*          Sf   = (float*)p;          p += (size_t)BSZ * SEQ * FCH * 4;
  float*          Hf   = (float*)p;          p += (size_t)BSZ * SEQ * FCH * 4;
  unsigned short* w0b  = (unsigned short*)p; p += (size_t)ICH * FCH * 2;
  unsigned short* w1b  = (unsigned short*)p; p += (size_t)KW * ICH * ICH * 2;
  unsigned short* w2b  = (unsigned short*)p; p += (size_t)FCH * ICH * 2;
  float*          P1   = (float*)p;          p += (size_t)BSZ * NCHUNK * ICH * 4;
  float*          P2   = (float*)p;          p += (size_t)BSZ * NCHUNK * ICH * 4;
  float*          MS   = (float*)p;          p += (size_t)BSZ * 2 * ICH * 4;

  zero_xpad_kernel<<<BSZ * 4 * FCH / 256, 256, 0, stream>>>(Xbf);
  addpos_T_kernel<<<dim3(SEQ / 64, FCH / 64, BSZ), 256, 0, stream>>>(inp, pos, Xbf);
  transpose_div_kernel<<<dim3(SEQ / 64, FCH / 64), 256, 0, stream>>>(divisor, divT);

  auto act_norm = [&](const float* src, unsigned short* dst, int M) {
    colred_kernel<<<dim3(M / 64, NCHUNK, BSZ), 256, 0, stream>>>(src, P1, P2, M);
    colfin_kernel<<<(BSZ * M) / 256, 256, 0, stream>>>(P1, P2, MS, M);
    colapply_kernel<<<dim3(M / 64, NCHUNK, BSZ), 256, 0, stream>>>(src, MS, dst, M);
  };

  auto run_ff = [&](const float* w0, const float* w1, const float* w2, float* dst) {
    cast_bf_kernel<<<(ICH * FCH) / 1024, 256, 0, stream>>>(w0, w0b);
    cast_w1_kernel<<<dim3(ICH / 256, ICH), 256, 0, stream>>>(w1, w1b);
    cast_bf_kernel<<<(FCH * ICH) / 1024, 256, 0, stream>>>(w2, w2b);
    // conv0: M=ICH, K=FCH
    gemm_mfma_kernel<1><<<dim3(SEQ / 128, ICH / 128, BSZ), 256, 0, stream>>>(
        Xbf, w0b, Cf, ICH, FCH);
    act_norm(Cf, T0b, ICH);
    // conv1: 5 fused causal taps, M=ICH, K=ICH
    gemm_mfma_kernel<5><<<dim3(SEQ / 128, ICH / 128, BSZ), 256, 0, stream>>>(
        T0b, w1b, Cf, ICH, ICH);
    act_norm(Cf, T0b, ICH);
    // conv2: M=FCH, K=ICH
    gemm_mfma_kernel<1><<<dim3(SEQ / 128, FCH / 128, BSZ), 256, 0, stream>>>(
        T0b, w2b, dst, FCH, ICH);
  };

  run_ff(w_[0], w_[1], w_[2], Df);  // depth
  run_ff(w_[3], w_[4], w_[5], Sf);  // scale
  run_ff(w_[6], w_[7], w_[8], Hf);  // shift

  combine_kernel<<<(BSZ * SEQ) / 4, 256, 0, stream>>>(Df, divT, Sf, Hf);

  // final act_norm over s (per (b,f)) on Df, then transpose + residual
  colred_kernel<<<dim3(FCH / 64, NCHUNK, BSZ), 256, 0, stream>>>(Df, P1, P2, FCH);
  colfin_kernel<<<(BSZ * FCH) / 256, 256, 0, stream>>>(P1, P2, MS, FCH);
  final_apply_kernel<<<dim3(SEQ / 64, FCH / 64, BSZ), 256, 0, stream>>>(
      Df, MS, inp, out);
}

// Round 4
// 1339.232 us; speedup vs baseline: 17.9212x; 1.2797x over previous
//
#include <hip/hip_runtime.h>
#include <math.h>

#define BSZ 4
#define FCH 1024
#define SEQ 2048
#define ICH 2048
#define KW  5
#define EPSV 1e-5f
#define RPAD 2244  // 4 front zero-pad + 2048 rows + slack
#define NCHUNK 16  // SEQ/128 row chunks for column reductions

typedef __attribute__((ext_vector_type(8))) short bf16x8;
typedef __attribute__((ext_vector_type(4))) float f32x4;
typedef __attribute__((ext_vector_type(4))) unsigned short us4;

__device__ __forceinline__ unsigned short f2bf(float f) {
  union { float f; unsigned u; } v; v.f = f;
  unsigned r = v.u + 0x7fff + ((v.u >> 16) & 1);  // round-to-nearest-even
  return (unsigned short)(r >> 16);
}

__device__ __forceinline__ void gload_lds16(const void* g, void* l) {
  __builtin_amdgcn_global_load_lds(
      (const __attribute__((address_space(1))) void*)g,
      (__attribute__((address_space(3))) void*)l, 16, 0, 0);
}

// ---------------- input transpose + pos add:  [b][f][s] -> bf16 [b][4+s][f]
__global__ __launch_bounds__(256) void addpos_T_kernel(
    const float* __restrict__ inp, const float* __restrict__ pos,
    unsigned short* __restrict__ X)
{
  __shared__ float t[64][65];
  const int s0 = blockIdx.x * 64, f0 = blockIdx.y * 64, b = blockIdx.z;
  const int a = threadIdx.x & 63, g = threadIdx.x >> 6;
  const float* ib = inp + (size_t)b * FCH * SEQ;
#pragma unroll
  for (int i = 0; i < 16; ++i) {
    const size_t o = (size_t)(f0 + g + i * 4) * SEQ + s0 + a;
    t[a][g + i * 4] = ib[o] + pos[o];
  }
  __syncthreads();
#pragma unroll
  for (int i = 0; i < 16; ++i)
    X[(size_t)b * RPAD * FCH + (size_t)(4 + s0 + g + i * 4) * FCH + f0 + a] =
        f2bf(t[g + i * 4][a]);
}

// zero the 4 leading pad rows of Xbf per batch
__global__ __launch_bounds__(256) void zero_xpad_kernel(unsigned short* __restrict__ X)
{
  const int i = blockIdx.x * 256 + threadIdx.x;  // < BSZ*4*FCH
  const int b = i / (4 * FCH);
  const int r = i % (4 * FCH);
  X[(size_t)b * RPAD * FCH + r] = 0;
}

// divisor [f][s] -> divT [s][f] fp32
__global__ __launch_bounds__(256) void transpose_div_kernel(
    const float* __restrict__ D, float* __restrict__ O)
{
  __shared__ float t[64][65];
  const int s0 = blockIdx.x * 64, f0 = blockIdx.y * 64;
  const int a = threadIdx.x & 63, g = threadIdx.x >> 6;
#pragma unroll
  for (int i = 0; i < 16; ++i)
    t[a][g + i * 4] = D[(size_t)(f0 + g + i * 4) * SEQ + s0 + a];
  __syncthreads();
#pragma unroll
  for (int i = 0; i < 16; ++i)
    O[(size_t)(s0 + g + i * 4) * FCH + f0 + a] = t[g + i * 4][a];
}

// ---------------- weight converts
__global__ __launch_bounds__(256) void cast_bf_kernel(
    const float* __restrict__ I, unsigned short* __restrict__ O)
{
  const size_t i = ((size_t)blockIdx.x * 256 + threadIdx.x) * 4;
  const float4 v = *(const float4*)(I + i);
  us4 o; o.x = f2bf(v.x); o.y = f2bf(v.y); o.z = f2bf(v.z); o.w = f2bf(v.w);
  *(us4*)(O + i) = o;
}

// W1 [m][c][k] fp32 -> O [k][m][c] bf16
__global__ __launch_bounds__(256) void cast_w1_kernel(
    const float* __restrict__ W, unsigned short* __restrict__ O)
{
  const int c = blockIdx.x * 256 + threadIdx.x;
  const int m = blockIdx.y;
  const float* s = W + ((size_t)m * ICH + c) * KW;
#pragma unroll
  for (int k = 0; k < KW; ++k)
    O[((size_t)k * ICH + m) * ICH + c] = f2bf(s[k]);
}

// ---------------- 256x(BN) double-buffered MFMA GEMM, tap-outer causal shift
// C[b][s][m] = sum_t sum_c A[b][4+s+t-off][c] * W[t][m][c]
// A bf16 [BSZ][RPAD][K] (rows 0..3 zero), W bf16 [NTAPS][M][K], C fp32 [b][s][m].
// BM=256, BK=64, 512 threads = 8 waves (2 s-halves x 4 m-cols).
// LDS: 2 x (A 32KB + B BN*128B), XOR-swizzled columns (c ^= (row&7)<<4),
// swizzle applied via pre-swizzled GLOBAL source (global_load_lds writes linear).
// One vmcnt(0)+barrier per K-tile; stage of tile t+1 issued at start of tile t.
template <int BN, int NTAPS>
__global__ __launch_bounds__(512, 2) void gemm256_kernel(
    const unsigned short* __restrict__ A, const unsigned short* __restrict__ W,
    float* __restrict__ C, int M, int K)
{
  extern __shared__ __align__(16) char lds[];
  constexpr int ABYTES = 32768;        // 256 rows x 128B
  constexpr int BBYTES = BN * 128;
  constexpr int BUF = ABYTES + BBYTES;
  constexpr int WN  = BN / 4;          // per-wave m extent (64 or 32)
  constexpr int JF  = BN / 64;         // j-frags per wave (4 or 2)
  constexpr int JF2 = BN / 128;        // j-frags per phase-half (2 or 1)

  const int tid = threadIdx.x;
  const int ln  = tid & 63;
  const int wv  = tid >> 6;
  const int wr  = wv >> 2;             // s half (128 rows)
  const int wc  = wv & 3;              // m quarter (WN cols)
  const int l15 = ln & 15;
  const int lhi = ln >> 4;

  const int s0 = blockIdx.x * 256;
  const int m0 = blockIdx.y * BN;
  const int b  = blockIdx.z;

  const char* Ab = (const char*)(A + (size_t)b * RPAD * K);
  const char* Wb = (const char*)W;
  const size_t MK = (size_t)M * K;
  const int KT = K >> 6;               // K-tiles of 64

  // staging: thread's linear LDS slot (row, col) -> pre-swizzled global col
  const int scs  = (((tid & 7) ^ ((tid >> 3) & 7)) << 4);
  // fragment reads: swizzled col bytes for kk=0,1
  const int rxor = (l15 & 7) << 4;
  const int cbx0 = (lhi * 16) ^ rxor;
  const int cbx1 = (lhi * 16 + 64) ^ rxor;

  f32x4 acc[8][JF] = {};

  auto STAGE = [&](int t, int k0, int pb) {
    const int roff = (NTAPS == 1) ? 4 : t;
    char* dst = lds + pb * BUF;
#pragma unroll
    for (int q = 0; q < 4; ++q) {
      const int row = (q * 512 + tid) >> 3;
      gload_lds16(Ab + (size_t)(s0 + row + roff) * ((size_t)K * 2) +
                      (size_t)(k0 * 2 + scs),
                  dst + q * 8192 + tid * 16);
    }
#pragma unroll
    for (int q = 0; q < BN / 64; ++q) {
      const int row = (q * 512 + tid) >> 3;
      gload_lds16(Wb + ((size_t)t * MK + (size_t)(m0 + row) * K + k0) * 2 + scs,
                  dst + ABYTES + q * 8192 + tid * 16);
    }
  };

  auto COMPUTE = [&](int pb) {
    const char* bb = lds + pb * BUF;
#pragma unroll
    for (int ih = 0; ih < 2; ++ih) {
      bf16x8 af[4][2];
#pragma unroll
      for (int i = 0; i < 4; ++i) {
        const int r = (wr * 128 + ih * 64 + i * 16 + l15) * 128;
        af[i][0] = *(const bf16x8*)(bb + r + cbx0);
        af[i][1] = *(const bf16x8*)(bb + r + cbx1);
      }
#pragma unroll
      for (int jh = 0; jh < 2; ++jh) {
        bf16x8 bfr[JF2][2];
#pragma unroll
        for (int j = 0; j < JF2; ++j) {
          const int r = ABYTES + (wc * WN + jh * (WN / 2) + j * 16 + l15) * 128;
          bfr[j][0] = *(const bf16x8*)(bb + r + cbx0);
          bfr[j][1] = *(const bf16x8*)(bb + r + cbx1);
        }
        __builtin_amdgcn_s_setprio(1);
#pragma unroll
        for (int i = 0; i < 4; ++i)
#pragma unroll
          for (int j = 0; j < JF2; ++j) {
            acc[ih * 4 + i][jh * JF2 + j] = __builtin_amdgcn_mfma_f32_16x16x32_bf16(
                af[i][0], bfr[j][0], acc[ih * 4 + i][jh * JF2 + j], 0, 0, 0);
            acc[ih * 4 + i][jh * JF2 + j] = __builtin_amdgcn_mfma_f32_16x16x32_bf16(
                af[i][1], bfr[j][1], acc[ih * 4 + i][jh * JF2 + j], 0, 0, 0);
          }
        __builtin_amdgcn_s_setprio(0);
      }
    }
  };

  STAGE(0, 0, 0);
  asm volatile("s_waitcnt vmcnt(0)" ::: "memory");
  __syncthreads();
  int p = 0;
  for (int t = 0; t < NTAPS; ++t) {
    for (int kt = 0; kt < KT; ++kt) {
      int ntp = t, nk = kt + 1;
      if (nk == KT) { nk = 0; ++ntp; }
      if (ntp < NTAPS) STAGE(ntp, nk * 64, p ^ 1);
      COMPUTE(p);
      asm volatile("s_waitcnt vmcnt(0)" ::: "memory");
      __syncthreads();
      p ^= 1;
    }
  }

  float* Cb = C + (size_t)b * SEQ * M;
#pragma unroll
  for (int i = 0; i < 8; ++i) {
    const int sb = s0 + wr * 128 + i * 16 + lhi * 4;
#pragma unroll
    for (int j = 0; j < JF; ++j) {
      const int m = m0 + wc * WN + j * 16 + l15;
#pragma unroll
      for (int r = 0; r < 4; ++r)
        Cb[(size_t)(sb + r) * M + m] = acc[i][j][r];
    }
  }
}

// ---------------- column act_norm, split into 3 parallel dispatches ----------
__global__ __launch_bounds__(256) void colred_kernel(
    const float* __restrict__ Cf, float* __restrict__ P1,
    float* __restrict__ P2, int M)
{
  const int b = blockIdx.z;
  const int mi = threadIdx.x & 63;
  const int sg = threadIdx.x >> 6;
  const int m = blockIdx.x * 64 + mi;
  const int s0 = blockIdx.y * 128;
  const float* src = Cf + ((size_t)b * SEQ + s0) * M + m;
  float sum = 0.f, sq = 0.f;
  for (int s = sg; s < 128; s += 4) {
    const float x = fmaxf(src[(size_t)s * M], 0.f);
    sum += x; sq += x * x;
  }
  __shared__ float rs[4][64], rq[4][64];
  rs[sg][mi] = sum; rq[sg][mi] = sq;
  __syncthreads();
  if (sg == 0) {
    const size_t o = ((size_t)b * NCHUNK + blockIdx.y) * M + m;
    P1[o] = rs[0][mi] + rs[1][mi] + rs[2][mi] + rs[3][mi];
    P2[o] = rq[0][mi] + rq[1][mi] + rq[2][mi] + rq[3][mi];
  }
}

__global__ __launch_bounds__(256) void colfin_kernel(
    const float* __restrict__ P1, const float* __restrict__ P2,
    float* __restrict__ MS, int M)
{
  const int i = blockIdx.x * 256 + threadIdx.x;  // < BSZ*M
  const int b = i / M, m = i % M;
  float S1 = 0.f, S2 = 0.f;
#pragma unroll
  for (int c = 0; c < NCHUNK; ++c) {
    S1 += P1[((size_t)b * NCHUNK + c) * M + m];
    S2 += P2[((size_t)b * NCHUNK + c) * M + m];
  }
  const float mean = S1 * (1.f / SEQ);
  const float ss = fmaxf(S2 - SEQ * mean * mean, 0.f);
  const float scl = sqrtf((float)SEQ) / (sqrtf(ss) + EPSV);
  MS[((size_t)b * 2 + 0) * M + m] = mean;
  MS[((size_t)b * 2 + 1) * M + m] = scl;
}

__global__ __launch_bounds__(256) void colapply_kernel(
    const float* __restrict__ Cf, const float* __restrict__ MS,
    unsigned short* __restrict__ Ob, int M)
{
  const int b = blockIdx.z;
  const int mi = threadIdx.x & 63;
  const int sg = threadIdx.x >> 6;
  const int m = blockIdx.x * 64 + mi;
  const int s0 = blockIdx.y * 128;
  const float mean = MS[((size_t)b * 2 + 0) * M + m];
  const float scl  = MS[((size_t)b * 2 + 1) * M + m];
  const float* src = Cf + ((size_t)b * SEQ + s0) * M + m;
  unsigned short* dst = Ob + ((size_t)b * RPAD + 4 + s0) * M + m;
  if (blockIdx.y == 0 && sg == 0) {
#pragma unroll
    for (int r = 0; r < 4; ++r) Ob[((size_t)b * RPAD + r) * M + m] = 0;
  }
  for (int s = sg; s < 128; s += 4)
    dst[(size_t)s * M] = f2bf((fmaxf(src[(size_t)s * M], 0.f) - mean) * scl);
}

// ---------------- cumsum over f (fast dim) + divide/scale/shift, in place on Dp
__global__ __launch_bounds__(256) void combine_kernel(
    float* __restrict__ Dp, const float* __restrict__ divT,
    const float* __restrict__ Sc, const float* __restrict__ Sh)
{
  const int row = blockIdx.x * 4 + (threadIdx.x >> 6);  // (b,s) flat
  const int b = row >> 11, s = row & 2047;
  const int ln = threadIdx.x & 63;
  const size_t base = ((size_t)b * SEQ + s) * FCH;
  const float* dv = divT + (size_t)s * FCH;
  float carry = 0.f;
  for (int c0 = 0; c0 < FCH; c0 += 64) {
    float x = Dp[base + c0 + ln];
#pragma unroll
    for (int d = 1; d < 64; d <<= 1) {
      const float t = __shfl_up(x, d, 64);
      if (ln >= d) x += t;
    }
    x += carry;
    carry = __shfl(x, 63, 64);
    Dp[base + c0 + ln] = x / dv[c0 + ln] * Sc[base + c0 + ln] + Sh[base + c0 + ln];
  }
}

// ---------------- final apply: out[b][f][s] = inp + (relu(Df)-mean)*scl, transposed
__global__ __launch_bounds__(256) void final_apply_kernel(
    const float* __restrict__ Df, const float* __restrict__ MS,
    const float* __restrict__ inp, float* __restrict__ out)
{
  __shared__ float tile[64][65];
  const int b = blockIdx.z;
  const int s0 = blockIdx.x * 64, f0 = blockIdx.y * 64;
  const int a = threadIdx.x & 63, g = threadIdx.x >> 6;
  const float mean = MS[((size_t)b * 2 + 0) * FCH + f0 + a];
  const float scl  = MS[((size_t)b * 2 + 1) * FCH + f0 + a];
#pragma unroll
  for (int i = 0; i < 16; ++i) {
    const int s = g + i * 4;
    const float x = fmaxf(Df[((size_t)b * SEQ + s0 + s) * FCH + f0 + a], 0.f);
    tile[s][a] = (x - mean) * scl;
  }
  __syncthreads();
#pragma unroll
  for (int i = 0; i < 16; ++i) {
    const int f = g + i * 4;
    const size_t o = ((size_t)b * FCH + f0 + f) * SEQ + s0 + a;
    out[o] = inp[o] + tile[a][f];
  }
}

extern "C" void kernel_launch(void* const* d_in, const int* in_sizes, int n_in,
                              void* d_out, int out_size, void* d_ws, size_t ws_size,
                              hipStream_t stream)
{
  const float* inp     = (const float*)d_in[0];
  const float* pos     = (const float*)d_in[1];
  const float* divisor = (const float*)d_in[2];
  const float* w_[9];
  for (int i = 0; i < 9; ++i) w_[i] = (const float*)d_in[3 + i];
  float* out = (float*)d_out;

  // workspace layout (~283 MB)
  char* p = (char*)d_ws;
  float*          divT = (float*)p;          p += (size_t)SEQ * FCH * 4;
  unsigned short* Xbf  = (unsigned short*)p; p += (size_t)BSZ * RPAD * FCH * 2;
  unsigned short* T0b  = (unsigned short*)p; p += (size_t)BSZ * RPAD * ICH * 2;
  float*          Cf   = (float*)p;          p += (size_t)BSZ * SEQ * ICH * 4;
  float*          Df   = (float*)p;          p += (size_t)BSZ * SEQ * FCH * 4;
  float*          Sf   = (float*)p;          p += (size_t)BSZ * SEQ * FCH * 4;
  float*          Hf   = (float*)p;          p += (size_t)BSZ * SEQ * FCH * 4;
  unsigned short* w0b  = (unsigned short*)p; p += (size_t)ICH * FCH * 2;
  unsigned short* w1b  = (unsigned short*)p; p += (size_t)KW * ICH * ICH * 2;
  unsigned short* w2b  = (unsigned short*)p; p += (size_t)FCH * ICH * 2;
  float*          P1   = (float*)p;          p += (size_t)BSZ * NCHUNK * ICH * 4;
  float*          P2   = (float*)p;          p += (size_t)BSZ * NCHUNK * ICH * 4;
  float*          MS   = (float*)p;          p += (size_t)BSZ * 2 * ICH * 4;

  // allow >64KB dynamic LDS for the GEMM instantiations
  hipFuncSetAttribute((const void*)gemm256_kernel<256, 1>,
                      hipFuncAttributeMaxDynamicSharedMemorySize, 131072);
  hipFuncSetAttribute((const void*)gemm256_kernel<256, 5>,
                      hipFuncAttributeMaxDynamicSharedMemorySize, 131072);
  hipFuncSetAttribute((const void*)gemm256_kernel<128, 1>,
                      hipFuncAttributeMaxDynamicSharedMemorySize, 98304);

  zero_xpad_kernel<<<BSZ * 4 * FCH / 256, 256, 0, stream>>>(Xbf);
  addpos_T_kernel<<<dim3(SEQ / 64, FCH / 64, BSZ), 256, 0, stream>>>(inp, pos, Xbf);
  transpose_div_kernel<<<dim3(SEQ / 64, FCH / 64), 256, 0, stream>>>(divisor, divT);

  auto act_norm = [&](const float* src, unsigned short* dst, int M) {
    colred_kernel<<<dim3(M / 64, NCHUNK, BSZ), 256, 0, stream>>>(src, P1, P2, M);
    colfin_kernel<<<(BSZ * M) / 256, 256, 0, stream>>>(P1, P2, MS, M);
    colapply_kernel<<<dim3(M / 64, NCHUNK, BSZ), 256, 0, stream>>>(src, MS, dst, M);
  };

  auto run_ff = [&](const float* w0, const float* w1, const float* w2, float* dst) {
    cast_bf_kernel<<<(ICH * FCH) / 1024, 256, 0, stream>>>(w0, w0b);
    cast_w1_kernel<<<dim3(ICH / 256, ICH), 256, 0, stream>>>(w1, w1b);
    cast_bf_kernel<<<(FCH * ICH) / 1024, 256, 0, stream>>>(w2, w2b);
    // conv0: M=ICH, K=FCH
    gemm256_kernel<256, 1><<<dim3(SEQ / 256, ICH / 256, BSZ), 512, 131072, stream>>>(
        Xbf, w0b, Cf, ICH, FCH);
    act_norm(Cf, T0b, ICH);
    // conv1: 5 causal taps (tap-outer), M=ICH, K=ICH
    gemm256_kernel<256, 5><<<dim3(SEQ / 256, ICH / 256, BSZ), 512, 131072, stream>>>(
        T0b, w1b, Cf, ICH, ICH);
    act_norm(Cf, T0b, ICH);
    // conv2: M=FCH, K=ICH (BN=128 keeps 256 blocks)
    gemm256_kernel<128, 1><<<dim3(SEQ / 256, FCH / 128, BSZ), 512, 98304, stream>>>(
        T0b, w2b, dst, FCH, ICH);
  };

  run_ff(w_[0], w_[1], w_[2], Df);  // depth
  run_ff(w_[3], w_[4], w_[5], Sf);  // scale
  run_ff(w_[6], w_[7], w_[8], Hf);  // shift

  combine_kernel<<<(BSZ * SEQ) / 4, 256, 0, stream>>>(Df, divT, Sf, Hf);

  // final act_norm over s (per (b,f)) on Df, then transpose + residual
  colred_kernel<<<dim3(FCH / 64, NCHUNK, BSZ), 256, 0, stream>>>(Df, P1, P2, FCH);
  colfin_kernel<<<(BSZ * FCH) / 256, 256, 0, stream>>>(P1, P2, MS, FCH);
  final_apply_kernel<<<dim3(SEQ / 64, FCH / 64, BSZ), 256, 0, stream>>>(
      Df, MS, inp, out);
}

// Round 5
// 1239.289 us; speedup vs baseline: 19.3665x; 1.0806x over previous
//
#include <hip/hip_runtime.h>
#include <math.h>

#define BSZ 4
#define FCH 1024
#define SEQ 2048
#define ICH 2048
#define KW  5
#define EPSV 1e-5f
#define RPAD 2244   // 4 front zero-pad + 2048 rows + slack
#define NCHF 16     // final-norm colred chunks (128 rows each)

typedef __attribute__((ext_vector_type(8))) short bf16x8;
typedef __attribute__((ext_vector_type(4))) float f32x4;
typedef __attribute__((ext_vector_type(4))) unsigned short us4;

__device__ __forceinline__ unsigned short f2bf(float f) {
  union { float f; unsigned u; } v; v.f = f;
  unsigned r = v.u + 0x7fff + ((v.u >> 16) & 1);  // round-to-nearest-even
  return (unsigned short)(r >> 16);
}
__device__ __forceinline__ float bf2f(unsigned short u) {
  union { unsigned u; float f; } v; v.u = (unsigned)u << 16; return v.f;
}

__device__ __forceinline__ void gload_lds16(const void* g, void* l) {
  __builtin_amdgcn_global_load_lds(
      (const __attribute__((address_space(1))) void*)g,
      (__attribute__((address_space(3))) void*)l, 16, 0, 0);
}

// ---------------- input transpose + pos add:  [b][f][s] -> bf16 [b][4+s][f]
__global__ __launch_bounds__(256) void addpos_T_kernel(
    const float* __restrict__ inp, const float* __restrict__ pos,
    unsigned short* __restrict__ X)
{
  __shared__ float t[64][65];
  const int s0 = blockIdx.x * 64, f0 = blockIdx.y * 64, b = blockIdx.z;
  const int a = threadIdx.x & 63, g = threadIdx.x >> 6;
  const float* ib = inp + (size_t)b * FCH * SEQ;
#pragma unroll
  for (int i = 0; i < 16; ++i) {
    const size_t o = (size_t)(f0 + g + i * 4) * SEQ + s0 + a;
    t[a][g + i * 4] = ib[o] + pos[o];
  }
  __syncthreads();
#pragma unroll
  for (int i = 0; i < 16; ++i)
    X[(size_t)b * RPAD * FCH + (size_t)(4 + s0 + g + i * 4) * FCH + f0 + a] =
        f2bf(t[g + i * 4][a]);
}

// zero the 4 leading pad rows of Xbf per batch
__global__ __launch_bounds__(256) void zero_xpad_kernel(unsigned short* __restrict__ X)
{
  const int i = blockIdx.x * 256 + threadIdx.x;  // < BSZ*4*FCH
  const int b = i / (4 * FCH);
  const int r = i % (4 * FCH);
  X[(size_t)b * RPAD * FCH + r] = 0;
}

// divisor [f][s] -> divT [s][f] fp32
__global__ __launch_bounds__(256) void transpose_div_kernel(
    const float* __restrict__ D, float* __restrict__ O)
{
  __shared__ float t[64][65];
  const int s0 = blockIdx.x * 64, f0 = blockIdx.y * 64;
  const int a = threadIdx.x & 63, g = threadIdx.x >> 6;
#pragma unroll
  for (int i = 0; i < 16; ++i)
    t[a][g + i * 4] = D[(size_t)(f0 + g + i * 4) * SEQ + s0 + a];
  __syncthreads();
#pragma unroll
  for (int i = 0; i < 16; ++i)
    O[(size_t)(s0 + g + i * 4) * FCH + f0 + a] = t[g + i * 4][a];
}

// ---------------- weight converts
__global__ __launch_bounds__(256) void cast_bf_kernel(
    const float* __restrict__ I, unsigned short* __restrict__ O)
{
  const size_t i = ((size_t)blockIdx.x * 256 + threadIdx.x) * 4;
  const float4 v = *(const float4*)(I + i);
  us4 o; o.x = f2bf(v.x); o.y = f2bf(v.y); o.z = f2bf(v.z); o.w = f2bf(v.w);
  *(us4*)(O + i) = o;
}

// W1 [m][c][k] fp32 -> O [k][m][c] bf16
__global__ __launch_bounds__(256) void cast_w1_kernel(
    const float* __restrict__ W, unsigned short* __restrict__ O)
{
  const int c = blockIdx.x * 256 + threadIdx.x;
  const int m = blockIdx.y;
  const float* s = W + ((size_t)m * ICH + c) * KW;
#pragma unroll
  for (int k = 0; k < KW; ++k)
    O[((size_t)k * ICH + m) * ICH + c] = f2bf(s[k]);
}

// ---------------- 256x(BN) double-buffered MFMA GEMM, tap-outer causal shift
// C[b][s][m] = sum_t sum_c A[b][4+s+t-off][c] * W[t][m][c]
// BF16OUT: C written as relu()'d bf16 AND per-(256-row-chunk, m) relu partial
// sums/sumsq written to P1/P2[b][8][M] (fused colred). Else C = raw fp32.
template <int BN, int NTAPS, int BF16OUT>
__global__ __launch_bounds__(512, 2) void gemm256_kernel(
    const unsigned short* __restrict__ A, const unsigned short* __restrict__ W,
    void* __restrict__ Cv, int M, int K,
    float* __restrict__ P1, float* __restrict__ P2)
{
  extern __shared__ __align__(16) char lds[];
  constexpr int ABYTES = 32768;        // 256 rows x 128B
  constexpr int BBYTES = BN * 128;
  constexpr int BUF = ABYTES + BBYTES;
  constexpr int WN  = BN / 4;          // per-wave m extent (64 or 32)
  constexpr int JF  = BN / 64;         // j-frags per wave (4 or 2)
  constexpr int JF2 = BN / 128;        // j-frags per phase-half (2 or 1)

  const int tid = threadIdx.x;
  const int ln  = tid & 63;
  const int wv  = tid >> 6;
  const int wr  = wv >> 2;             // s half (128 rows)
  const int wc  = wv & 3;              // m quarter (WN cols)
  const int l15 = ln & 15;
  const int lhi = ln >> 4;

  const int s0 = blockIdx.x * 256;
  const int m0 = blockIdx.y * BN;
  const int b  = blockIdx.z;

  const char* Ab = (const char*)(A + (size_t)b * RPAD * K);
  const char* Wb = (const char*)W;
  const size_t MK = (size_t)M * K;
  const int KT = K >> 6;               // K-tiles of 64

  // staging: thread's linear LDS slot (row, col) -> pre-swizzled global col
  const int scs  = (((tid & 7) ^ ((tid >> 3) & 7)) << 4);
  // fragment reads: swizzled col bytes for kk=0,1
  const int rxor = (l15 & 7) << 4;
  const int cbx0 = (lhi * 16) ^ rxor;
  const int cbx1 = (lhi * 16 + 64) ^ rxor;

  f32x4 acc[8][JF] = {};

  auto STAGE = [&](int t, int k0, int pb) {
    const int roff = (NTAPS == 1) ? 4 : t;
    char* dst = lds + pb * BUF;
#pragma unroll
    for (int q = 0; q < 4; ++q) {
      const int row = (q * 512 + tid) >> 3;
      gload_lds16(Ab + (size_t)(s0 + row + roff) * ((size_t)K * 2) +
                      (size_t)(k0 * 2 + scs),
                  dst + q * 8192 + tid * 16);
    }
#pragma unroll
    for (int q = 0; q < BN / 64; ++q) {
      const int row = (q * 512 + tid) >> 3;
      gload_lds16(Wb + ((size_t)t * MK + (size_t)(m0 + row) * K + k0) * 2 + scs,
                  dst + ABYTES + q * 8192 + tid * 16);
    }
  };

  auto COMPUTE = [&](int pb) {
    const char* bb = lds + pb * BUF;
#pragma unroll
    for (int ih = 0; ih < 2; ++ih) {
      bf16x8 af[4][2];
#pragma unroll
      for (int i = 0; i < 4; ++i) {
        const int r = (wr * 128 + ih * 64 + i * 16 + l15) * 128;
        af[i][0] = *(const bf16x8*)(bb + r + cbx0);
        af[i][1] = *(const bf16x8*)(bb + r + cbx1);
      }
#pragma unroll
      for (int jh = 0; jh < 2; ++jh) {
        bf16x8 bfr[JF2][2];
#pragma unroll
        for (int j = 0; j < JF2; ++j) {
          const int r = ABYTES + (wc * WN + jh * (WN / 2) + j * 16 + l15) * 128;
          bfr[j][0] = *(const bf16x8*)(bb + r + cbx0);
          bfr[j][1] = *(const bf16x8*)(bb + r + cbx1);
        }
        __builtin_amdgcn_s_setprio(1);
#pragma unroll
        for (int i = 0; i < 4; ++i)
#pragma unroll
          for (int j = 0; j < JF2; ++j) {
            acc[ih * 4 + i][jh * JF2 + j] = __builtin_amdgcn_mfma_f32_16x16x32_bf16(
                af[i][0], bfr[j][0], acc[ih * 4 + i][jh * JF2 + j], 0, 0, 0);
            acc[ih * 4 + i][jh * JF2 + j] = __builtin_amdgcn_mfma_f32_16x16x32_bf16(
                af[i][1], bfr[j][1], acc[ih * 4 + i][jh * JF2 + j], 0, 0, 0);
          }
        __builtin_amdgcn_s_setprio(0);
      }
    }
  };

  STAGE(0, 0, 0);
  asm volatile("s_waitcnt vmcnt(0)" ::: "memory");
  __syncthreads();
  int p = 0;
  for (int t = 0; t < NTAPS; ++t) {
    for (int kt = 0; kt < KT; ++kt) {
      int ntp = t, nk = kt + 1;
      if (nk == KT) { nk = 0; ++ntp; }
      if (ntp < NTAPS) STAGE(ntp, nk * 64, p ^ 1);
      COMPUTE(p);
      asm volatile("s_waitcnt vmcnt(0)" ::: "memory");
      __syncthreads();
      p ^= 1;
    }
  }

  if constexpr (BF16OUT) {
    // relu'd bf16 C + fused column partial sums (chunk = this block's 256 rows)
    unsigned short* Cb = (unsigned short*)Cv + (size_t)b * SEQ * M;
    float S[JF] = {}, Q[JF] = {};
#pragma unroll
    for (int i = 0; i < 8; ++i) {
      const int sb = s0 + wr * 128 + i * 16 + lhi * 4;
#pragma unroll
      for (int j = 0; j < JF; ++j) {
        const int m = m0 + wc * WN + j * 16 + l15;
#pragma unroll
        for (int r = 0; r < 4; ++r) {
          const float x = fmaxf(acc[i][j][r], 0.f);
          S[j] += x; Q[j] += x * x;
          Cb[(size_t)(sb + r) * M + m] = f2bf(x);
        }
      }
    }
#pragma unroll
    for (int j = 0; j < JF; ++j) {
      S[j] += __shfl_xor(S[j], 16, 64); S[j] += __shfl_xor(S[j], 32, 64);
      Q[j] += __shfl_xor(Q[j], 16, 64); Q[j] += __shfl_xor(Q[j], 32, 64);
    }
    float* SL = (float*)lds;                 // [2][4][JF][16]
    float* QL = SL + 2 * 4 * JF * 16;
    if (lhi == 0) {
#pragma unroll
      for (int j = 0; j < JF; ++j) {
        SL[((wr * 4 + wc) * JF + j) * 16 + l15] = S[j];
        QL[((wr * 4 + wc) * JF + j) * 16 + l15] = Q[j];
      }
    }
    __syncthreads();
    if (wr == 0 && lhi == 0) {
#pragma unroll
      for (int j = 0; j < JF; ++j) {
        const int m = m0 + wc * WN + j * 16 + l15;
        const size_t o = ((size_t)b * (SEQ / 256) + blockIdx.x) * M + m;
        P1[o] = SL[((0 * 4 + wc) * JF + j) * 16 + l15] +
                SL[((1 * 4 + wc) * JF + j) * 16 + l15];
        P2[o] = QL[((0 * 4 + wc) * JF + j) * 16 + l15] +
                QL[((1 * 4 + wc) * JF + j) * 16 + l15];
      }
    }
  } else {
    float* Cb = (float*)Cv + (size_t)b * SEQ * M;
#pragma unroll
    for (int i = 0; i < 8; ++i) {
      const int sb = s0 + wr * 128 + i * 16 + lhi * 4;
#pragma unroll
      for (int j = 0; j < JF; ++j) {
        const int m = m0 + wc * WN + j * 16 + l15;
#pragma unroll
        for (int r = 0; r < 4; ++r)
          Cb[(size_t)(sb + r) * M + m] = acc[i][j][r];
      }
    }
  }
}

// ---------------- colred (final norm only): partial sums over 128-row chunks
__global__ __launch_bounds__(256) void colred_kernel(
    const float* __restrict__ Cf, float* __restrict__ P1,
    float* __restrict__ P2, int M)
{
  const int b = blockIdx.z;
  const int mi = threadIdx.x & 63;
  const int sg = threadIdx.x >> 6;
  const int m = blockIdx.x * 64 + mi;
  const int s0 = blockIdx.y * 128;
  const float* src = Cf + ((size_t)b * SEQ + s0) * M + m;
  float sum = 0.f, sq = 0.f;
  for (int s = sg; s < 128; s += 4) {
    const float x = fmaxf(src[(size_t)s * M], 0.f);
    sum += x; sq += x * x;
  }
  __shared__ float rs[4][64], rq[4][64];
  rs[sg][mi] = sum; rq[sg][mi] = sq;
  __syncthreads();
  if (sg == 0) {
    const size_t o = ((size_t)b * NCHF + blockIdx.y) * M + m;
    P1[o] = rs[0][mi] + rs[1][mi] + rs[2][mi] + rs[3][mi];
    P2[o] = rq[0][mi] + rq[1][mi] + rq[2][mi] + rq[3][mi];
  }
}

// colfin: mean/scale per (b,m) from nchunk partials.  MS [b][2][M]
__global__ __launch_bounds__(256) void colfin_kernel(
    const float* __restrict__ P1, const float* __restrict__ P2,
    float* __restrict__ MS, int M, int nchunk)
{
  const int i = blockIdx.x * 256 + threadIdx.x;  // < BSZ*M
  const int b = i / M, m = i % M;
  float S1 = 0.f, S2 = 0.f;
  for (int c = 0; c < nchunk; ++c) {
    S1 += P1[((size_t)b * nchunk + c) * M + m];
    S2 += P2[((size_t)b * nchunk + c) * M + m];
  }
  const float mean = S1 * (1.f / SEQ);
  const float ss = fmaxf(S2 - SEQ * mean * mean, 0.f);
  const float scl = sqrtf((float)SEQ) / (sqrtf(ss) + EPSV);
  MS[((size_t)b * 2 + 0) * M + m] = mean;
  MS[((size_t)b * 2 + 1) * M + m] = scl;
}

// colapply: (relu'd bf16 C - mean)*scl -> bf16 padded activation buffer
__global__ __launch_bounds__(256) void colapply_kernel(
    const unsigned short* __restrict__ Cf, const float* __restrict__ MS,
    unsigned short* __restrict__ Ob, int M)
{
  const int b = blockIdx.z;
  const int mi = threadIdx.x & 63;
  const int sg = threadIdx.x >> 6;
  const int m = blockIdx.x * 64 + mi;
  const int s0 = blockIdx.y * 128;
  const float mean = MS[((size_t)b * 2 + 0) * M + m];
  const float scl  = MS[((size_t)b * 2 + 1) * M + m];
  const unsigned short* src = Cf + ((size_t)b * SEQ + s0) * M + m;
  unsigned short* dst = Ob + ((size_t)b * RPAD + 4 + s0) * M + m;
  if (blockIdx.y == 0 && sg == 0) {
#pragma unroll
    for (int r = 0; r < 4; ++r) Ob[((size_t)b * RPAD + r) * M + m] = 0;
  }
  for (int s = sg; s < 128; s += 4)
    dst[(size_t)s * M] = f2bf((bf2f(src[(size_t)s * M]) - mean) * scl);
}

// ---------------- cumsum over f (fast dim) + divide/scale/shift, in place on Dp
__global__ __launch_bounds__(256) void combine_kernel(
    float* __restrict__ Dp, const float* __restrict__ divT,
    const float* __restrict__ Sc, const float* __restrict__ Sh)
{
  const int row = blockIdx.x * 4 + (threadIdx.x >> 6);  // (b,s) flat
  const int b = row >> 11, s = row & 2047;
  const int ln = threadIdx.x & 63;
  const size_t base = ((size_t)b * SEQ + s) * FCH;
  const float* dv = divT + (size_t)s * FCH;
  float carry = 0.f;
  for (int c0 = 0; c0 < FCH; c0 += 64) {
    float x = Dp[base + c0 + ln];
#pragma unroll
    for (int d = 1; d < 64; d <<= 1) {
      const float t = __shfl_up(x, d, 64);
      if (ln >= d) x += t;
    }
    x += carry;
    carry = __shfl(x, 63, 64);
    Dp[base + c0 + ln] = x / dv[c0 + ln] * Sc[base + c0 + ln] + Sh[base + c0 + ln];
  }
}

// ---------------- final apply: out[b][f][s] = inp + (relu(Df)-mean)*scl, transposed
__global__ __launch_bounds__(256) void final_apply_kernel(
    const float* __restrict__ Df, const float* __restrict__ MS,
    const float* __restrict__ inp, float* __restrict__ out)
{
  __shared__ float tile[64][65];
  const int b = blockIdx.z;
  const int s0 = blockIdx.x * 64, f0 = blockIdx.y * 64;
  const int a = threadIdx.x & 63, g = threadIdx.x >> 6;
  const float mean = MS[((size_t)b * 2 + 0) * FCH + f0 + a];
  const float scl  = MS[((size_t)b * 2 + 1) * FCH + f0 + a];
#pragma unroll
  for (int i = 0; i < 16; ++i) {
    const int s = g + i * 4;
    const float x = fmaxf(Df[((size_t)b * SEQ + s0 + s) * FCH + f0 + a], 0.f);
    tile[s][a] = (x - mean) * scl;
  }
  __syncthreads();
#pragma unroll
  for (int i = 0; i < 16; ++i) {
    const int f = g + i * 4;
    const size_t o = ((size_t)b * FCH + f0 + f) * SEQ + s0 + a;
    out[o] = inp[o] + tile[a][f];
  }
}

extern "C" void kernel_launch(void* const* d_in, const int* in_sizes, int n_in,
                              void* d_out, int out_size, void* d_ws, size_t ws_size,
                              hipStream_t stream)
{
  const float* inp     = (const float*)d_in[0];
  const float* pos     = (const float*)d_in[1];
  const float* divisor = (const float*)d_in[2];
  const float* w_[9];
  for (int i = 0; i < 9; ++i) w_[i] = (const float*)d_in[3 + i];
  float* out = (float*)d_out;

  // workspace layout (~250 MB)
  char* p = (char*)d_ws;
  float*          divT = (float*)p;          p += (size_t)SEQ * FCH * 4;
  unsigned short* Xbf  = (unsigned short*)p; p += (size_t)BSZ * RPAD * FCH * 2;
  unsigned short* T0b  = (unsigned short*)p; p += (size_t)BSZ * RPAD * ICH * 2;
  unsigned short* Cfb  = (unsigned short*)p; p += (size_t)BSZ * SEQ * ICH * 2;
  float*          Df   = (float*)p;          p += (size_t)BSZ * SEQ * FCH * 4;
  float*          Sf   = (float*)p;          p += (size_t)BSZ * SEQ * FCH * 4;
  float*          Hf   = (float*)p;          p += (size_t)BSZ * SEQ * FCH * 4;
  unsigned short* w0b  = (unsigned short*)p; p += (size_t)ICH * FCH * 2;
  unsigned short* w1b  = (unsigned short*)p; p += (size_t)KW * ICH * ICH * 2;
  unsigned short* w2b  = (unsigned short*)p; p += (size_t)FCH * ICH * 2;
  float*          P1   = (float*)p;          p += (size_t)BSZ * NCHF * ICH * 4;
  float*          P2   = (float*)p;          p += (size_t)BSZ * NCHF * ICH * 4;
  float*          MS   = (float*)p;          p += (size_t)BSZ * 2 * ICH * 4;

  // allow >64KB dynamic LDS for the GEMM instantiations
  hipFuncSetAttribute((const void*)gemm256_kernel<256, 1, 1>,
                      hipFuncAttributeMaxDynamicSharedMemorySize, 131072);
  hipFuncSetAttribute((const void*)gemm256_kernel<256, 5, 1>,
                      hipFuncAttributeMaxDynamicSharedMemorySize, 131072);
  hipFuncSetAttribute((const void*)gemm256_kernel<128, 1, 0>,
                      hipFuncAttributeMaxDynamicSharedMemorySize, 98304);

  zero_xpad_kernel<<<BSZ * 4 * FCH / 256, 256, 0, stream>>>(Xbf);
  addpos_T_kernel<<<dim3(SEQ / 64, FCH / 64, BSZ), 256, 0, stream>>>(inp, pos, Xbf);
  transpose_div_kernel<<<dim3(SEQ / 64, FCH / 64), 256, 0, stream>>>(divisor, divT);

  // colfin+colapply after a BF16OUT GEMM (stats already in P1/P2, 8 chunks)
  auto act_norm = [&](unsigned short* dst, int M) {
    colfin_kernel<<<(BSZ * M) / 256, 256, 0, stream>>>(P1, P2, MS, M, 8);
    colapply_kernel<<<dim3(M / 64, NCHF, BSZ), 256, 0, stream>>>(Cfb, MS, dst, M);
  };

  auto run_ff = [&](const float* w0, const float* w1, const float* w2, float* dst) {
    cast_bf_kernel<<<(ICH * FCH) / 1024, 256, 0, stream>>>(w0, w0b);
    cast_w1_kernel<<<dim3(ICH / 256, ICH), 256, 0, stream>>>(w1, w1b);
    cast_bf_kernel<<<(FCH * ICH) / 1024, 256, 0, stream>>>(w2, w2b);
    // conv0: M=ICH, K=FCH
    gemm256_kernel<256, 1, 1><<<dim3(SEQ / 256, ICH / 256, BSZ), 512, 131072, stream>>>(
        Xbf, w0b, Cfb, ICH, FCH, P1, P2);
    act_norm(T0b, ICH);
    // conv1: 5 causal taps (tap-outer), M=ICH, K=ICH
    gemm256_kernel<256, 5, 1><<<dim3(SEQ / 256, ICH / 256, BSZ), 512, 131072, stream>>>(
        T0b, w1b, Cfb, ICH, ICH, P1, P2);
    act_norm(T0b, ICH);
    // conv2: M=FCH, K=ICH, fp32 out (BN=128 keeps 256 blocks)
    gemm256_kernel<128, 1, 0><<<dim3(SEQ / 256, FCH / 128, BSZ), 512, 98304, stream>>>(
        T0b, w2b, dst, FCH, ICH, P1, P2);
  };

  run_ff(w_[0], w_[1], w_[2], Df);  // depth
  run_ff(w_[3], w_[4], w_[5], Sf);  // scale
  run_ff(w_[6], w_[7], w_[8], Hf);  // shift

  combine_kernel<<<(BSZ * SEQ) / 4, 256, 0, stream>>>(Df, divT, Sf, Hf);

  // final act_norm over s (per (b,f)) on combined Df, then transpose + residual
  colred_kernel<<<dim3(FCH / 64, NCHF, BSZ), 256, 0, stream>>>(Df, P1, P2, FCH);
  colfin_kernel<<<(BSZ * FCH) / 256, 256, 0, stream>>>(P1, P2, MS, FCH, NCHF);
  final_apply_kernel<<<dim3(SEQ / 64, FCH / 64, BSZ), 256, 0, stream>>>(
      Df, MS, inp, out);
}